// Round 4
// baseline (775.928 us; speedup 1.0000x reference)
//
#include <hip/hip_runtime.h>

#define BATCH   128
#define NUM_IN  4096
#define LVL     8
#define HID     32768
#define KH      32
#define OUTN    256
#define KOUT    64
#define SCALEA  4.9f
#define INV255  (1.0f / 255.0f)

// Workspace layout:
//   in_u : bf16 input acts, node-major packed pairs. in_u[n*64 + lane] holds
//          batch {2*lane, 2*lane+1} of node n (n < 4096). 1 MB.
//   hid  : u8 fixed-point hidden acts (sigmoid outputs in (0,1), scale 1/255),
//          hid[(n-4096)*64 + lane] is a ushort holding batch pair. 33.5 MB.
// Rationale (R3 post-mortem): gather stream is downstream-BW-limited
// (~3.1 TB/s beyond-L2); halving bytes/act is the only lever. u8 abs err
// 1/510 ~ bf16 rel err for sigmoid outputs; inputs stay bf16.

__device__ __forceinline__ unsigned short f2bf(float f) {
    unsigned u = __float_as_uint(f);
    u += 0x7FFFu + ((u >> 16) & 1u);   // round-to-nearest-even
    return (unsigned short)(u >> 16);
}
__device__ __forceinline__ float bf_lo(unsigned u) { return __uint_as_float(u << 16); }
__device__ __forceinline__ float bf_hi(unsigned u) { return __uint_as_float(u & 0xFFFF0000u); }

// ---------------------------------------------------------------------------
// Transpose x [B, NUM_IN] f32 -> in_u [node][b] bf16 packed pairs
// ---------------------------------------------------------------------------
__global__ __launch_bounds__(256) void transpose_x(const float* __restrict__ x,
                                                   unsigned* __restrict__ in_u) {
    __shared__ float lds[64][129];
    const int n0 = blockIdx.x * 64;
    const int t  = threadIdx.x;
    #pragma unroll
    for (int it = 0; it < 32; ++it) {
        int i = it * 256 + t;
        int b = i >> 6;
        int n = i & 63;
        lds[n][b] = x[b * NUM_IN + n0 + n];
    }
    __syncthreads();
    #pragma unroll
    for (int it = 0; it < 16; ++it) {
        int i  = it * 256 + t;      // 0..4095 : 64 nodes x 64 uint-pairs
        int n  = i >> 6;
        int bp = i & 63;
        unsigned lo = f2bf(lds[n][2 * bp]);
        unsigned hi = f2bf(lds[n][2 * bp + 1]);
        in_u[(n0 + n) * 64 + bp] = lo | (hi << 16);
    }
}

// ---------------------------------------------------------------------------
// One hidden level: one wave per hidden unit; idx/w wave-uniform (scalar);
// lane owns batch pair. Source j < NUM_IN -> bf16 input region (256B/gather),
// else u8 hidden region (128B/gather). Branch is wave-uniform (scalar cmp).
// Output: sigmoid in (0,1) quantized to u8 (scale 1/255), 128B wave store.
// ---------------------------------------------------------------------------
__global__ __launch_bounds__(256) void hidden_level(const unsigned* __restrict__ in_u,
                                                    unsigned short* __restrict__ hid,
                                                    const int* __restrict__ idx,
                                                    const float* __restrict__ w,
                                                    int hbase) {  // = l*HID
    const int lane = threadIdx.x & 63;
    int h = (blockIdx.x << 2) + (threadIdx.x >> 6);
    h = __builtin_amdgcn_readfirstlane(h);
    const int*   ip = idx + h * KH;
    const float* wp = w   + h * KH;

    float ax = 0.f, ay = 0.f;
    #pragma unroll
    for (int k = 0; k < KH; ++k) {
        int   j  = __builtin_amdgcn_readfirstlane(ip[k]);
        float wk = wp[k];
        if (j < NUM_IN) {
            unsigned u = in_u[(unsigned)j * 64 + lane];
            ax = fmaf(wk, bf_lo(u), ax);
            ay = fmaf(wk, bf_hi(u), ay);
        } else {
            unsigned t = hid[(unsigned)(j - NUM_IN) * 64 + lane];
            float sw = wk * INV255;
            ax = fmaf(sw, (float)(t & 0xFFu), ax);
            ay = fmaf(sw, (float)(t >> 8),   ay);
        }
    }

    float rx = 1.f / (1.f + __expf(-SCALEA * ax));
    float ry = 1.f / (1.f + __expf(-SCALEA * ay));
    unsigned qx = __float2uint_rn(rx * 255.f);
    unsigned qy = __float2uint_rn(ry * 255.f);
    hid[(unsigned)(hbase + h) * 64 + lane] = (unsigned short)(qx | (qy << 8));
}

// ---------------------------------------------------------------------------
// Output layer: one wave per output unit, KO=64; f32 output in out[b][o].
// ---------------------------------------------------------------------------
__global__ __launch_bounds__(256) void output_layer(const unsigned* __restrict__ in_u,
                                                    const unsigned short* __restrict__ hid,
                                                    const int* __restrict__ idx,
                                                    const float* __restrict__ w,
                                                    float* __restrict__ out) {
    const int lane = threadIdx.x & 63;
    int o = (blockIdx.x << 2) + (threadIdx.x >> 6);
    o = __builtin_amdgcn_readfirstlane(o);
    const int*   ip = idx + o * KOUT;
    const float* wp = w   + o * KOUT;

    float ax = 0.f, ay = 0.f;
    #pragma unroll
    for (int k = 0; k < KOUT; ++k) {
        int   j  = __builtin_amdgcn_readfirstlane(ip[k]);
        float wk = wp[k];
        if (j < NUM_IN) {
            unsigned u = in_u[(unsigned)j * 64 + lane];
            ax = fmaf(wk, bf_lo(u), ax);
            ay = fmaf(wk, bf_hi(u), ay);
        } else {
            unsigned t = hid[(unsigned)(j - NUM_IN) * 64 + lane];
            float sw = wk * INV255;
            ax = fmaf(sw, (float)(t & 0xFFu), ax);
            ay = fmaf(sw, (float)(t >> 8),   ay);
        }
    }
    out[(2 * lane + 0) * OUTN + o] = 1.f / (1.f + __expf(-SCALEA * ax));
    out[(2 * lane + 1) * OUTN + o] = 1.f / (1.f + __expf(-SCALEA * ay));
}

extern "C" void kernel_launch(void* const* d_in, const int* in_sizes, int n_in,
                              void* d_out, int out_size, void* d_ws, size_t ws_size,
                              hipStream_t stream) {
    // setup_inputs() order: x, w_hidden, w_out, idx_hidden, idx_out
    const float* x          = (const float*)d_in[0];
    const float* w_hidden   = (const float*)d_in[1];
    const float* w_out      = (const float*)d_in[2];
    const int*   idx_hidden = (const int*)  d_in[3];
    const int*   idx_out    = (const int*)  d_in[4];
    float* out = (float*)d_out;

    unsigned*       in_u = (unsigned*)d_ws;                          // 1 MB
    unsigned short* hid  = (unsigned short*)((char*)d_ws + (size_t)NUM_IN * 64 * 4);  // 33.5 MB

    transpose_x<<<NUM_IN / 64, 256, 0, stream>>>(x, in_u);

    for (int l = 0; l < LVL; ++l) {
        hidden_level<<<HID / 4, 256, 0, stream>>>(
            in_u, hid,
            idx_hidden + (size_t)l * HID * KH,
            w_hidden   + (size_t)l * HID * KH,
            l * HID);
    }

    output_layer<<<OUTN / 4, 256, 0, stream>>>(in_u, hid, idx_out, w_out, out);
}

// Round 5
// 319.130 us; speedup vs baseline: 2.4314x; 2.4314x over previous
//
#include <hip/hip_runtime.h>

#define BATCH   128
#define NUM_IN  4096
#define LVL     8
#define HID     32768
#define KH      32
#define OUTN    256
#define KOUT    64
#define SCALEA  4.9f
#define INV255  (1.0f / 255.0f)
#define ZREL    (LVL * HID)   // zeroed dummy hidden slot (hidden-relative index)

// Workspace layout (bytes):
//   in_f  @ 0         : f32 inputs node-major, in_f[n*128 + b]          2 MB
//   hid   @ 2,097,152 : u8 hidden acts, node-major; node stride 128 B
//                       (64 ushorts, lane holds batch pair) + 1 zero
//                       dummy node at ZREL                              33.5 MB
//   e_idx @35,651,712 : per (l-1,h,k) branchless hidden-relative index
//                       (input entries -> ZREL, whose act == 0)         28.0 MB
//   iin   @65,011,840 : compact input-entry list ((k<<16)|j)            28.0 MB
//   cnt   @94,371,968 : input-entry count per (l-1,h)                   0.9 MB
//   e_o/iin_o/cnt_o   : same for output layer                           0.13 MB
// R4 post-mortem: the per-k branch serialized gathers (VGPR=4, 0.7 TB/s).
// Preprocessing restores R2's branchless batched-gather loop at u8 bytes.

__global__ __launch_bounds__(256) void transpose_x(const float* __restrict__ x,
                                                   float* __restrict__ in_f,
                                                   unsigned short* __restrict__ hid) {
    __shared__ float lds[64][129];
    const int n0 = blockIdx.x * 64;
    const int t  = threadIdx.x;
    #pragma unroll
    for (int it = 0; it < 32; ++it) {
        int i = it * 256 + t;
        int b = i >> 6;
        int n = i & 63;
        lds[n][b] = x[b * NUM_IN + n0 + n];
    }
    __syncthreads();
    #pragma unroll
    for (int it = 0; it < 32; ++it) {
        int i = it * 256 + t;
        int n = i >> 7;
        int b = i & 127;
        in_f[(n0 + n) * BATCH + b] = lds[n][b];
    }
    if (blockIdx.x == 0 && t < 64) hid[(unsigned)ZREL * 64 + t] = 0;  // zero dummy node
}

// One wave per (level-1, h) unit; lane k<32 handles entry k.
__global__ __launch_bounds__(256) void prep_hidden(const int* __restrict__ idx_hidden,
                                                   unsigned* __restrict__ e_idx,
                                                   unsigned* __restrict__ iin,
                                                   unsigned* __restrict__ cnt) {
    int unit = blockIdx.x * 4 + (threadIdx.x >> 6);   // 0 .. 7*HID-1
    int lane = threadIdx.x & 63;
    int lv   = unit >> 15;                            // 0..6 -> level lv+1
    int h    = unit & (HID - 1);
    const int* ip = idx_hidden + ((size_t)(lv + 1) * HID + h) * KH;
    int  j    = (lane < KH) ? ip[lane] : NUM_IN;
    bool isin = (lane < KH) && (j < NUM_IN);
    unsigned long long mask = __ballot(isin);
    size_t eo = (size_t)unit * KH;
    if (lane < KH) e_idx[eo + lane] = isin ? (unsigned)ZREL : (unsigned)(j - NUM_IN);
    if (isin) {
        int pos = __popcll(mask & ((1ull << lane) - 1ull));
        iin[eo + pos] = ((unsigned)lane << 16) | (unsigned)j;
    }
    if (lane == 0) cnt[unit] = (unsigned)__popcll(mask);
}

__global__ __launch_bounds__(256) void prep_out(const int* __restrict__ idx_out,
                                                unsigned* __restrict__ e_o,
                                                unsigned* __restrict__ iin_o,
                                                unsigned* __restrict__ cnt_o) {
    int o    = blockIdx.x * 4 + (threadIdx.x >> 6);   // 0..255
    int lane = threadIdx.x & 63;
    const int* ip = idx_out + (size_t)o * KOUT;
    int  j    = ip[lane];
    bool isin = (j < NUM_IN);
    unsigned long long mask = __ballot(isin);
    size_t eo = (size_t)o * KOUT;
    e_o[eo + lane] = isin ? (unsigned)ZREL : (unsigned)(j - NUM_IN);
    if (isin) {
        int pos = __popcll(mask & ((1ull << lane) - 1ull));
        iin_o[eo + pos] = ((unsigned)lane << 16) | (unsigned)j;
    }
    if (lane == 0) cnt_o[o] = (unsigned)__popcll(mask);
}

// Level 0: all sources are inputs (randint maxval = NUM_IN). Branchless f32 gathers.
__global__ __launch_bounds__(256) void level0(const float* __restrict__ in_f,
                                              unsigned short* __restrict__ hid,
                                              const int* __restrict__ idx,
                                              const float* __restrict__ w) {
    const int lane = threadIdx.x & 63;
    int h = (blockIdx.x << 2) + (threadIdx.x >> 6);
    h = __builtin_amdgcn_readfirstlane(h);
    const int*   ip = idx + h * KH;
    const float* wp = w   + h * KH;
    float ax = 0.f, ay = 0.f;
    #pragma unroll
    for (int k = 0; k < KH; ++k) {
        int   j  = __builtin_amdgcn_readfirstlane(ip[k]);
        float wk = wp[k];
        const float2 v = *(const float2*)(in_f + (unsigned)j * BATCH + 2 * lane);
        ax = fmaf(wk, v.x, ax);
        ay = fmaf(wk, v.y, ay);
    }
    unsigned qx = __float2uint_rn(255.f / (1.f + __expf(-SCALEA * ax)));
    unsigned qy = __float2uint_rn(255.f / (1.f + __expf(-SCALEA * ay)));
    hid[(unsigned)h * 64 + lane] = (unsigned short)(qx | (qy << 8));
}

// Levels 1..7: short rolled prefix over input entries (L2-resident f32),
// then fixed branchless 32x u8 gather (dummies hit the zero node).
__global__ __launch_bounds__(256) void deep_level(const float* __restrict__ in_f,
                                                  unsigned short* __restrict__ hid,
                                                  const unsigned* __restrict__ e_idx_l,
                                                  const unsigned* __restrict__ iin_l,
                                                  const unsigned* __restrict__ cnt_l,
                                                  const float* __restrict__ w_l,
                                                  int hbase) {
    const int lane = threadIdx.x & 63;
    int h = (blockIdx.x << 2) + (threadIdx.x >> 6);
    h = __builtin_amdgcn_readfirstlane(h);
    const unsigned* ep = e_idx_l + (size_t)h * KH;
    const float*    wp = w_l     + (size_t)h * KH;

    float ax = 0.f, ay = 0.f;
    int c = __builtin_amdgcn_readfirstlane((int)cnt_l[h]);
    for (int s = 0; s < c; ++s) {
        unsigned e = (unsigned)__builtin_amdgcn_readfirstlane((int)iin_l[(size_t)h * KH + s]);
        float wk = wp[e >> 16];
        const float2 v = *(const float2*)(in_f + (e & 0xFFFFu) * BATCH + 2 * lane);
        ax = fmaf(wk, v.x, ax);
        ay = fmaf(wk, v.y, ay);
    }
    #pragma unroll
    for (int k = 0; k < KH; ++k) {
        unsigned jp = (unsigned)__builtin_amdgcn_readfirstlane((int)ep[k]);
        float sw = wp[k] * INV255;
        unsigned t = hid[jp * 64 + lane];
        ax = fmaf(sw, (float)(t & 0xFFu), ax);
        ay = fmaf(sw, (float)(t >> 8),   ay);
    }
    unsigned qx = __float2uint_rn(255.f / (1.f + __expf(-SCALEA * ax)));
    unsigned qy = __float2uint_rn(255.f / (1.f + __expf(-SCALEA * ay)));
    hid[(unsigned)(hbase + h) * 64 + lane] = (unsigned short)(qx | (qy << 8));
}

__global__ __launch_bounds__(256) void output_layer(const float* __restrict__ in_f,
                                                    const unsigned short* __restrict__ hid,
                                                    const unsigned* __restrict__ e_o,
                                                    const unsigned* __restrict__ iin_o,
                                                    const unsigned* __restrict__ cnt_o,
                                                    const float* __restrict__ w,
                                                    float* __restrict__ out) {
    const int lane = threadIdx.x & 63;
    int o = (blockIdx.x << 2) + (threadIdx.x >> 6);
    o = __builtin_amdgcn_readfirstlane(o);
    const unsigned* ep = e_o + (size_t)o * KOUT;
    const float*    wp = w   + (size_t)o * KOUT;

    float ax = 0.f, ay = 0.f;
    int c = __builtin_amdgcn_readfirstlane((int)cnt_o[o]);
    for (int s = 0; s < c; ++s) {
        unsigned e = (unsigned)__builtin_amdgcn_readfirstlane((int)iin_o[(size_t)o * KOUT + s]);
        float wk = wp[e >> 16];
        const float2 v = *(const float2*)(in_f + (e & 0xFFFFu) * BATCH + 2 * lane);
        ax = fmaf(wk, v.x, ax);
        ay = fmaf(wk, v.y, ay);
    }
    #pragma unroll
    for (int k = 0; k < KOUT; ++k) {
        unsigned jp = (unsigned)__builtin_amdgcn_readfirstlane((int)ep[k]);
        float sw = wp[k] * INV255;
        unsigned t = hid[jp * 64 + lane];
        ax = fmaf(sw, (float)(t & 0xFFu), ax);
        ay = fmaf(sw, (float)(t >> 8),   ay);
    }
    out[(2 * lane + 0) * OUTN + o] = 1.f / (1.f + __expf(-SCALEA * ax));
    out[(2 * lane + 1) * OUTN + o] = 1.f / (1.f + __expf(-SCALEA * ay));
}

extern "C" void kernel_launch(void* const* d_in, const int* in_sizes, int n_in,
                              void* d_out, int out_size, void* d_ws, size_t ws_size,
                              hipStream_t stream) {
    // setup_inputs() order: x, w_hidden, w_out, idx_hidden, idx_out
    const float* x          = (const float*)d_in[0];
    const float* w_hidden   = (const float*)d_in[1];
    const float* w_out      = (const float*)d_in[2];
    const int*   idx_hidden = (const int*)  d_in[3];
    const int*   idx_out    = (const int*)  d_in[4];
    float* out = (float*)d_out;

    char* ws = (char*)d_ws;
    float*          in_f  = (float*)          (ws + 0);
    unsigned short* hid   = (unsigned short*) (ws + 2097152);
    unsigned*       e_idx = (unsigned*)       (ws + 35651712);
    unsigned*       iin   = (unsigned*)       (ws + 65011840);
    unsigned*       cnt   = (unsigned*)       (ws + 94371968);
    unsigned*       e_o   = (unsigned*)       (ws + 95289472);
    unsigned*       iin_o = (unsigned*)       (ws + 95355008);
    unsigned*       cnt_o = (unsigned*)       (ws + 95420544);
    // total 95,421,568 bytes

    transpose_x<<<NUM_IN / 64, 256, 0, stream>>>(x, in_f, hid);
    prep_hidden<<<7 * HID / 4, 256, 0, stream>>>(idx_hidden, e_idx, iin, cnt);
    prep_out<<<OUTN / 4, 256, 0, stream>>>(idx_out, e_o, iin_o, cnt_o);

    level0<<<HID / 4, 256, 0, stream>>>(in_f, hid, idx_hidden, w_hidden);
    for (int l = 1; l < LVL; ++l) {
        deep_level<<<HID / 4, 256, 0, stream>>>(
            in_f, hid,
            e_idx + (size_t)(l - 1) * HID * KH,
            iin   + (size_t)(l - 1) * HID * KH,
            cnt   + (size_t)(l - 1) * HID,
            w_hidden + (size_t)l * HID * KH,
            l * HID);
    }
    output_layer<<<OUTN / 4, 256, 0, stream>>>(in_f, hid, e_o, iin_o, cnt_o, w_out, out);
}